// Round 2
// baseline (66.763 us; speedup 1.0000x reference)
//
#include <hip/hip_runtime.h>

// PairWiseLoss, fused single kernel.
//   loss = sum_g sum_{i in pos_g, j in neg_g} max(0, 1-(s_i-s_j)) / sum_g np_g*nn_g
// segment_ids sorted -> per-graph range via 2-round parallel probe (not serial
// binary search: 64 blocks = 1/CU gives no latency hiding, so dependent-load
// chains are the dominant cost).

#define NUM_GRAPHS 64
#define BLOCK 256
#define CAP 4096   // per-class LDS capacity (expected seg len ~192); 32KB LDS

__global__ __launch_bounds__(BLOCK)
void pairwise_fused(const float* __restrict__ scores,
                    const int* __restrict__ labels,
                    const int* __restrict__ seg,
                    int n,
                    float* __restrict__ g_tot,
                    unsigned long long* __restrict__ g_cnt,
                    unsigned int* __restrict__ g_done,
                    float* __restrict__ out) {
    __shared__ float s_pos[CAP];
    __shared__ float s_neg[CAP];
    __shared__ int s_cp, s_cn, s_loA, s_loB, s_start, s_end;
    __shared__ float sm[BLOCK / 64];
    __shared__ unsigned long long smc[BLOCK / 64];

    const int g    = blockIdx.x;
    const int tid  = threadIdx.x;
    const int lane = tid & 63;
    const int wave = tid >> 6;
    const unsigned long long below = (1ull << lane) - 1ull;

    if (tid == 0) { s_cp = 0; s_cn = 0; s_loA = -1; s_loB = -1; s_start = 0; s_end = 0; }
    __syncthreads();

    // ---- Phase A: coarse probe. 256 samples at stride; per-wave ballot ->
    // at most one LDS atomicMax per wave per target.
    const int stride = (n + BLOCK - 1) / BLOCK;  // 48 for N=12288
    if (stride <= 64) {
        int pos = tid * stride;
        int v = (pos < n) ? seg[pos] : 0x7fffffff;
        unsigned long long mA = __ballot(v < g);
        unsigned long long mB = __ballot(v < g + 1);
        if (mA && lane == 63 - __clzll(mA)) atomicMax(&s_loA, pos);
        if (mB && lane == 63 - __clzll(mB)) atomicMax(&s_loB, pos);
        __syncthreads();

        // ---- Phase B: fine probe of the <=stride-wide window, one wave per target.
        if (wave == 0) {
            int L = s_loA;
            int idx = L + 1 + lane;
            bool pred = (lane < stride) && (idx < n) && (seg[idx] < g);
            unsigned long long m = __ballot(pred);
            if (lane == 0) s_start = L + 1 + __popcll(m);
        } else if (wave == 1) {
            int L = s_loB;
            int idx = L + 1 + lane;
            bool pred = (lane < stride) && (idx < n) && (seg[idx] < g + 1);
            unsigned long long m = __ballot(pred);
            if (lane == 0) s_end = L + 1 + __popcll(m);
        }
    } else {
        // Robustness fallback (never taken at N=12288): serial binary search.
        if (tid == 0) {
            int lo = 0, hi = n;
            while (lo < hi) { int m = (lo + hi) >> 1; if (seg[m] < g) lo = m + 1; else hi = m; }
            s_start = lo;
            lo = 0; hi = n;
            while (lo < hi) { int m = (lo + hi) >> 1; if (seg[m] < g + 1) lo = m + 1; else hi = m; }
            s_end = lo;
        }
    }
    __syncthreads();
    const int start = s_start, end = s_end;

    // ---- Compact by class into LDS: ballot ranks, one LDS atomic per wave per class.
    for (int bi = start + wave * 64; bi < end; bi += BLOCK) {
        int i = bi + lane;
        bool valid = i < end;
        int   lab = valid ? labels[i] : 0;
        float sc  = valid ? scores[i] : 0.0f;
        bool isp = valid && (lab != 0);
        bool isn = valid && (lab == 0);
        unsigned long long pm = __ballot(isp);
        unsigned long long nm = __ballot(isn);
        int pb = 0, nb = 0;
        if (lane == 0) {
            pb = atomicAdd(&s_cp, __popcll(pm));
            nb = atomicAdd(&s_cn, __popcll(nm));
        }
        pb = __shfl(pb, 0, 64);
        nb = __shfl(nb, 0, 64);
        if (isp) { int r = pb + __popcll(pm & below); if (r < CAP) s_pos[r] = sc; }
        else if (isn) { int r = nb + __popcll(nm & below); if (r < CAP) s_neg[r] = sc; }
    }
    __syncthreads();

    const int np = s_cp, nn = s_cn;
    float local = 0.0f;
    unsigned long long pairs = 0ull;

    if (np <= CAP && nn <= CAP) {
        // LDS-resident double loop; inner reads are wave-uniform broadcasts.
        for (int p = tid; p < np; p += BLOCK) {
            const float base = 1.0f - s_pos[p];
            int j = 0;
            for (; j + 4 <= nn; j += 4) {
                local += fmaxf(base + s_neg[j],     0.0f);
                local += fmaxf(base + s_neg[j + 1], 0.0f);
                local += fmaxf(base + s_neg[j + 2], 0.0f);
                local += fmaxf(base + s_neg[j + 3], 0.0f);
            }
            for (; j < nn; ++j) local += fmaxf(base + s_neg[j], 0.0f);
        }
        if (tid == 0) pairs = (unsigned long long)np * (unsigned long long)nn;
    } else {
        // Pathological fallback: global brute force.
        for (int i = start + tid; i < end; i += BLOCK) {
            if (labels[i] != 0) {
                const float base = 1.0f - scores[i];
                for (int j = start; j < end; ++j) {
                    if (labels[j] == 0) { local += fmaxf(base + scores[j], 0.0f); pairs++; }
                }
            }
        }
    }

    // ---- Block reduce (wave shuffle + LDS across 4 waves).
    for (int off = 32; off; off >>= 1) {
        local += __shfl_down(local, off, 64);
        pairs += __shfl_down(pairs, off, 64);
    }
    if (lane == 0) { sm[wave] = local; smc[wave] = pairs; }
    __syncthreads();

    if (tid == 0) {
        float tot = 0.0f;
        unsigned long long c = 0ull;
        #pragma unroll
        for (int w = 0; w < BLOCK / 64; ++w) { tot += sm[w]; c += smc[w]; }
        atomicAdd(g_tot, tot);
        atomicAdd(g_cnt, c);
        __threadfence();
        unsigned int ticket = atomicAdd(g_done, 1u);
        if (ticket == gridDim.x - 1) {
            // Read back via atomic RMW (device-scope coherent across XCDs).
            float T = atomicAdd(g_tot, 0.0f);
            unsigned long long C = atomicAdd(g_cnt, 0ull);
            out[0] = (C > 0) ? (T / (float)C) : 0.0f;
        }
    }
}

extern "C" void kernel_launch(void* const* d_in, const int* in_sizes, int n_in,
                              void* d_out, int out_size, void* d_ws, size_t ws_size,
                              hipStream_t stream) {
    const float* scores = (const float*)d_in[0];
    const int*   labels = (const int*)d_in[1];
    const int*   seg    = (const int*)d_in[2];
    float*       out    = (float*)d_out;
    const int n = in_sizes[0];

    // ws layout: [0:4) float tot | [8:16) ull cnt | [16:20) uint done
    float*              g_tot  = (float*)d_ws;
    unsigned long long* g_cnt  = (unsigned long long*)((char*)d_ws + 8);
    unsigned int*       g_done = (unsigned int*)((char*)d_ws + 16);

    hipMemsetAsync(d_ws, 0, 24, stream);  // async -> captures as a graph memset node
    pairwise_fused<<<NUM_GRAPHS, BLOCK, 0, stream>>>(scores, labels, seg, n,
                                                     g_tot, g_cnt, g_done, out);
}

// Round 3
// 61.852 us; speedup vs baseline: 1.0794x; 1.0794x over previous
//
#include <hip/hip_runtime.h>

// PairWiseLoss: per-graph (pos,neg) hinge mean over sorted segment_ids.
//   loss = sum_g sum_{i in pos_g, j in neg_g} max(0, 1-(s_i-s_j)) / sum_g np_g*nn_g
//
// Structure (R3): two tiny kernels, deterministic plain stores between them
// (kernel-boundary coherence). No memset node, no device atomics — R2 showed
// the memset+ticket fusion costs more than a second 1-wave launch.
// Kernel 1 hides the probe->load dependency by speculatively staging a
// +-SLACK window around the expected segment into LDS (probe and staging
// loads are independent -> one latency round instead of three).

#define NUM_GRAPHS 64
#define BLOCK 256
#define SLACK 384          // 8 sigma of the binomial boundary deviation (~48)
#define WCAP 1024          // window capacity (avg 192 + 2*384 = 960 <= 1024)
#define CAP 1024           // per-class compacted capacity (np,nn <= window)

__global__ __launch_bounds__(BLOCK)
void pairwise_per_graph(const float* __restrict__ scores,
                        const int* __restrict__ labels,
                        const int* __restrict__ seg,
                        int n,
                        float* __restrict__ tots,
                        long long* __restrict__ cnts) {
    __shared__ float s_wsc[WCAP];       // staged window scores
    __shared__ int   s_wlb[WCAP];       // staged window labels
    __shared__ float s_pos[CAP];
    __shared__ float s_neg[CAP];
    __shared__ int s_cp, s_cn, s_loA, s_loB, s_start, s_end;
    __shared__ float sm[BLOCK / 64];
    __shared__ unsigned long long smc[BLOCK / 64];

    const int g    = blockIdx.x;
    const int tid  = threadIdx.x;
    const int lane = tid & 63;
    const int wave = tid >> 6;
    const unsigned long long below = (1ull << lane) - 1ull;

    if (tid == 0) { s_cp = 0; s_cn = 0; s_loA = -1; s_loB = -1; s_start = 0; s_end = 0; }

    // ---- Speculative window staging (independent of the probe; overlaps it).
    const int avg = n / NUM_GRAPHS;
    int wlo = g * avg - SLACK;       if (wlo < 0) wlo = 0;
    int whi = (g + 1) * avg + SLACK; if (whi > n) whi = n;
    const int wlen = whi - wlo;
    if (wlen <= WCAP) {
        for (int k = tid; k < wlen; k += BLOCK) {
            s_wsc[k] = scores[wlo + k];
            s_wlb[k] = labels[wlo + k];
        }
    }

    // ---- Parallel probe for [start, end): coarse stride sample + 1-wave refine.
    const int stride = (n + BLOCK - 1) / BLOCK;      // 48 for N=12288
    __syncthreads();                                  // covers s_* init
    if (stride <= 64) {
        int pos = tid * stride;
        int v = (pos < n) ? seg[pos] : 0x7fffffff;
        unsigned long long mA = __ballot(v < g);
        unsigned long long mB = __ballot(v < g + 1);
        if (mA && lane == 63 - __clzll(mA)) atomicMax(&s_loA, pos);
        if (mB && lane == 63 - __clzll(mB)) atomicMax(&s_loB, pos);
        __syncthreads();
        if (wave == 0) {
            int L = s_loA;
            int idx = L + 1 + lane;
            bool pred = (lane < stride) && (idx < n) && (seg[idx] < g);
            unsigned long long m = __ballot(pred);
            if (lane == 0) s_start = L + 1 + __popcll(m);
        } else if (wave == 1) {
            int L = s_loB;
            int idx = L + 1 + lane;
            bool pred = (lane < stride) && (idx < n) && (seg[idx] < g + 1);
            unsigned long long m = __ballot(pred);
            if (lane == 0) s_end = L + 1 + __popcll(m);
        }
    } else {
        if (tid == 0) {
            int lo = 0, hi = n;
            while (lo < hi) { int m = (lo + hi) >> 1; if (seg[m] < g) lo = m + 1; else hi = m; }
            s_start = lo;
            lo = 0; hi = n;
            while (lo < hi) { int m = (lo + hi) >> 1; if (seg[m] < g + 1) lo = m + 1; else hi = m; }
            s_end = lo;
        }
    }
    __syncthreads();
    const int start = s_start, end = s_end;
    const bool windowed = (wlen <= WCAP) && (start >= wlo) && (end <= whi);

    // ---- Compact by class (ballot ranks; one LDS atomic per wave per class).
    for (int bi = start + wave * 64; bi < end; bi += BLOCK) {
        int i = bi + lane;
        bool valid = i < end;
        int   lab = 0;
        float sc  = 0.0f;
        if (valid) {
            if (windowed) { lab = s_wlb[i - wlo]; sc = s_wsc[i - wlo]; }
            else          { lab = labels[i];      sc = scores[i];      }
        }
        bool isp = valid && (lab != 0);
        bool isn = valid && (lab == 0);
        unsigned long long pm = __ballot(isp);
        unsigned long long nm = __ballot(isn);
        int pb = 0, nb = 0;
        if (lane == 0) {
            pb = atomicAdd(&s_cp, __popcll(pm));
            nb = atomicAdd(&s_cn, __popcll(nm));
        }
        pb = __shfl(pb, 0, 64);
        nb = __shfl(nb, 0, 64);
        if (isp)      { int r = pb + __popcll(pm & below); if (r < CAP) s_pos[r] = sc; }
        else if (isn) { int r = nb + __popcll(nm & below); if (r < CAP) s_neg[r] = sc; }
    }
    __syncthreads();

    const int np = s_cp, nn = s_cn;
    float local = 0.0f;
    unsigned long long pairs = 0ull;

    if (np <= CAP && nn <= CAP) {
        // LDS-resident double loop; inner reads are wave-uniform broadcasts.
        for (int p = tid; p < np; p += BLOCK) {
            const float base = 1.0f - s_pos[p];
            int j = 0;
            for (; j + 4 <= nn; j += 4) {
                local += fmaxf(base + s_neg[j],     0.0f);
                local += fmaxf(base + s_neg[j + 1], 0.0f);
                local += fmaxf(base + s_neg[j + 2], 0.0f);
                local += fmaxf(base + s_neg[j + 3], 0.0f);
            }
            for (; j < nn; ++j) local += fmaxf(base + s_neg[j], 0.0f);
        }
        if (tid == 0) pairs = (unsigned long long)np * (unsigned long long)nn;
    } else {
        // Pathological fallback: global brute force.
        for (int i = start + tid; i < end; i += BLOCK) {
            if (labels[i] != 0) {
                const float base = 1.0f - scores[i];
                for (int j = start; j < end; ++j) {
                    if (labels[j] == 0) { local += fmaxf(base + scores[j], 0.0f); pairs++; }
                }
            }
        }
    }

    // ---- Block reduce.
    for (int off = 32; off; off >>= 1) {
        local += __shfl_down(local, off, 64);
        pairs += __shfl_down(pairs, off, 64);
    }
    if (lane == 0) { sm[wave] = local; smc[wave] = pairs; }
    __syncthreads();

    if (tid == 0) {
        float tot = 0.0f;
        unsigned long long c = 0ull;
        #pragma unroll
        for (int w = 0; w < BLOCK / 64; ++w) { tot += sm[w]; c += smc[w]; }
        tots[g] = tot;
        cnts[g] = (long long)c;
    }
}

__global__ __launch_bounds__(64)
void pairwise_finalize(const long long* __restrict__ cnts,
                       const float* __restrict__ tots,
                       float* __restrict__ out) {
    const int t = threadIdx.x;  // 64 threads == 1 wave == NUM_GRAPHS
    float tot = tots[t];
    long long c = cnts[t];
    for (int off = 32; off; off >>= 1) {
        tot += __shfl_down(tot, off, 64);
        c   += __shfl_down(c,   off, 64);
    }
    if (t == 0) out[0] = (c > 0) ? (tot / (float)c) : 0.0f;
}

extern "C" void kernel_launch(void* const* d_in, const int* in_sizes, int n_in,
                              void* d_out, int out_size, void* d_ws, size_t ws_size,
                              hipStream_t stream) {
    const float* scores = (const float*)d_in[0];
    const int*   labels = (const int*)d_in[1];
    const int*   seg    = (const int*)d_in[2];
    float*       out    = (float*)d_out;
    const int n = in_sizes[0];

    long long* cnts = (long long*)d_ws;
    float*     tots = (float*)((char*)d_ws + NUM_GRAPHS * sizeof(long long));

    pairwise_per_graph<<<NUM_GRAPHS, BLOCK, 0, stream>>>(scores, labels, seg, n, tots, cnts);
    pairwise_finalize<<<1, 64, 0, stream>>>(cnts, tots, out);
}